// Round 7
// baseline (517.028 us; speedup 1.0000x reference)
//
#include <hip/hip_runtime.h>
#include <hip/hip_bf16.h>

// AUGRU (DIEN) fused recurrent kernel. fp32 I/O, bf16 MFMA compute.
// B=2048, T=200, D=H=128. Block = 8 batch rows (256 blocks, 1/CU), 256 thr.
// Round 10: 1-step software pipeline of the x-dependent GEMM parts.
//  - cand x-part (8 MFMAs, reg operands) moved BEFORE SYNC B: overlaps the
//    gate-h ds_read latency; post-barrier cand chain halves.
//  - gate x-part of step t+1 (16 MFMAs + afx(t+1) reads) moved into the
//    post-SYNC-B segment: overlaps cand epilogue (shfl/tanh); removes the
//    afx read latency from the top of step t+1. Gate accumulators carry
//    across SYNC A.
// Base (R8, measured 271.7us kernel / 501.1us harness): 4-wave, register
// h/u state, LDS-only barriers, bank conflicts 9.39e6.

#define BB   2048
#define TT   200
#define DD   128
#define HH   128
#define NG   256
#define BM   8
#define SB   136     // bf16 tile row stride (shorts): 68 dwords = 4 mod 32
#define NTH  256

typedef __attribute__((ext_vector_type(8))) __bf16 bf16x8;
typedef __attribute__((ext_vector_type(4))) float  f32x4;

#define MFMA(a, b, c) __builtin_amdgcn_mfma_f32_16x16x32_bf16((a), (b), (c), 0, 0, 0)

union bfu { __bf16 b; unsigned short u; };
__device__ __forceinline__ unsigned short f2bf(float f) { bfu c; c.b = (__bf16)f; return c.u; }
__device__ __forceinline__ __bf16 f2bfv(float f) { return (__bf16)f; }
__device__ __forceinline__ float sigm(float x) { return __builtin_amdgcn_rcpf(1.0f + __expf(-x)); }

// Barrier with LDS-ordering only (no vmcnt drain; x-prefetch + OUT stores
// stay in flight across steps). Cross-wave ordering here is LDS-only.
__device__ __forceinline__ void lds_barrier() {
    __builtin_amdgcn_sched_barrier(0);
    asm volatile("s_waitcnt lgkmcnt(0)" ::: "memory");
    __builtin_amdgcn_s_barrier();
    __builtin_amdgcn_sched_barrier(0);
}

// gate GEMM x-part: 16 MFMAs accumulating into a0..a7 (uses bgf[0..3][0..3])
#define GATE_X_PART(FX)                                                       \
    a0 = MFMA(FX[0], bgf[0][0], a0); a2 = MFMA(FX[0], bgf[1][0], a2);         \
    a4 = MFMA(FX[0], bgf[2][0], a4); a6 = MFMA(FX[0], bgf[3][0], a6);         \
    a1 = MFMA(FX[1], bgf[0][1], a1); a3 = MFMA(FX[1], bgf[1][1], a3);         \
    a5 = MFMA(FX[1], bgf[2][1], a5); a7 = MFMA(FX[1], bgf[3][1], a7);         \
    a0 = MFMA(FX[2], bgf[0][2], a0); a2 = MFMA(FX[2], bgf[1][2], a2);         \
    a4 = MFMA(FX[2], bgf[2][2], a4); a6 = MFMA(FX[2], bgf[3][2], a6);         \
    a1 = MFMA(FX[3], bgf[0][3], a1); a3 = MFMA(FX[3], bgf[1][3], a3);         \
    a5 = MFMA(FX[3], bgf[2][3], a5); a7 = MFMA(FX[3], bgf[3][3], a7)

#define ZERO_A                                                                \
    a0 = (f32x4){0.f,0.f,0.f,0.f}; a1 = (f32x4){0.f,0.f,0.f,0.f};             \
    a2 = (f32x4){0.f,0.f,0.f,0.f}; a3 = (f32x4){0.f,0.f,0.f,0.f};             \
    a4 = (f32x4){0.f,0.f,0.f,0.f}; a5 = (f32x4){0.f,0.f,0.f,0.f};             \
    a6 = (f32x4){0.f,0.f,0.f,0.f}; a7 = (f32x4){0.f,0.f,0.f,0.f}

__global__ __launch_bounds__(NTH, 1)
void augru_kernel(const float* __restrict__ X,    // [B,T,D]
                  const float* __restrict__ ATT,  // [B,T]
                  const int*   __restrict__ SL,   // [B]
                  const float* __restrict__ WG,   // [256,256]
                  const float* __restrict__ BG,   // [256]
                  const float* __restrict__ WC,   // [256,128]
                  const float* __restrict__ BC,   // [128]
                  float*       __restrict__ OUT)  // [B,T,H]
{
    __shared__ unsigned short xb[2][16 * SB];  // x_t double buffer, bf16, rows 8..15 = 0
    __shared__ unsigned short hb[16 * SB];     // h bf16 (A-frag source), rows 8..15 = 0
    __shared__ unsigned short rh[16 * SB];     // r*h bf16, rows 8..15 = 0
    __shared__ float attall[BM * TT];
    __shared__ int   slbuf[BM];

    const int tid  = threadIdx.x;
    const int wave = tid >> 6;       // 0..3
    const int lane = tid & 63;
    const int quad = lane >> 4;
    const int l16  = lane & 15;
    const int b0   = blockIdx.x * BM;
    const int qq   = quad & 1;       // row-group select after redistribution
    const int top  = quad >> 1;
    const int r0   = 4 * qq + 2 * top;   // this lane handles rows r0, r0+1

    // ---------------- one-time init ----------------
    for (int i = tid; i < 2 * 16 * SB; i += NTH) xb[0][i] = 0;   // both buffers
    for (int i = tid; i < 16 * SB; i += NTH) hb[i] = 0;
    for (int i = tid; i < 16 * SB; i += NTH) rh[i] = 0;
    for (int i = tid; i < BM * TT; i += NTH) attall[i] = ATT[(long)b0 * TT + i];
    if (tid < BM) slbuf[tid] = SL[b0 + tid];

    // Columns this thread owns (cand / r-gate / h / out): c0, c1 = c0+16.
    // u-gate cols: c0+128, c1+128.
    const int c0 = wave * 32 + l16;
    const int c1 = c0 + 16;
    const float bgr0 = BG[c0],      bgr1 = BG[c1];        // r-gate biases
    const float bgu0 = BG[c0 + HH], bgu1 = BG[c1 + HH];   // u-gate biases
    const float bc0v = BC[c0],      bc1v = BC[c1];        // cand biases

    // Weight B-fragments (bf16) in registers.
    // B-frag (16x16x32): lane holds B[k = kk*32 + quad*8 + j][col]
    bf16x8 bgf[4][8], bcf[2][8];
    {
        #pragma unroll
        for (int kk = 0; kk < 8; ++kk) {
            bf16x8 t0, t1, t2, t3, t4, t5;
            #pragma unroll
            for (int j = 0; j < 8; ++j) {
                const int k = kk * 32 + quad * 8 + j;
                t0[j] = f2bfv(WG[k * NG + c0]);
                t1[j] = f2bfv(WG[k * NG + c1]);
                t2[j] = f2bfv(WG[k * NG + c0 + HH]);
                t3[j] = f2bfv(WG[k * NG + c1 + HH]);
                t4[j] = f2bfv(WC[k * HH + c0]);
                t5[j] = f2bfv(WC[k * HH + c1]);
            }
            bgf[0][kk] = t0; bgf[1][kk] = t1; bgf[2][kk] = t2; bgf[3][kk] = t3;
            bcf[0][kk] = t4; bcf[1][kk] = t5;
        }
    }
    __syncthreads();   // full barrier once (init loads must land)

    int tmax = 0;
    #pragma unroll
    for (int r = 0; r < BM; ++r) tmax = max(tmax, slbuf[r]);
    const int sl0 = slbuf[r0], sl1 = slbuf[r0 + 1];

    // Persistent per-thread state: h (fp32) for (rows r0,r0+1) x (cols c0,c1).
    float h00 = 0.f, h01 = 0.f, h10 = 0.f, h11 = 0.f;   // hXY: X=row, Y=col

    const int srow = tid >> 5;   // 0..7
    const int sseg = tid & 31;

    // Gate accumulators (carry the x-part across SYNC A).
    f32x4 a0, a1, a2, a3, a4, a5, a6, a7;
    ZERO_A;

    // prologue: stage x(0), prefetch x(1)
    float4 xpre;
    bf16x8 afx[4];
    if (tmax > 0) {
        xpre = *(const float4*)&X[((long)(b0 + srow) * TT + 0) * DD + sseg * 4];
        ushort4 v; v.x = f2bf(xpre.x); v.y = f2bf(xpre.y); v.z = f2bf(xpre.z); v.w = f2bf(xpre.w);
        *(ushort4*)&xb[0][srow * SB + sseg * 4] = v;
        if (tmax > 1)
            xpre = *(const float4*)&X[((long)(b0 + srow) * TT + 1) * DD + sseg * 4];
    }
    lds_barrier();   // x(0) visible (x(1) prefetch stays in flight)
    if (tmax > 0) {
        #pragma unroll
        for (int kk = 0; kk < 4; ++kk)
            afx[kk] = *(const bf16x8*)&xb[0][l16 * SB + kk * 32 + quad * 8];
        GATE_X_PART(afx);   // gate x-part for t=0
    }

    // ---------------- time loop ----------------
    for (int t = 0; t < tmax; ++t) {
        // entering: a0..a7 = gate x-part(t); afx = afx(t) in registers.

        // attention scores for this step
        const float at0 = attall[r0 * TT + t];
        const float at1 = attall[(r0 + 1) * TT + t];

        // ---- gate h-part (LDS reads) + cand x-part (pure reg) ----
        f32x4 q0 = {0.f,0.f,0.f,0.f}, q1 = {0.f,0.f,0.f,0.f};
        f32x4 q2 = {0.f,0.f,0.f,0.f}, q3 = {0.f,0.f,0.f,0.f};
        {
            const bf16x8 afh0 = *(const bf16x8*)&hb[l16 * SB + 0 * 32 + quad * 8];
            const bf16x8 afh1 = *(const bf16x8*)&hb[l16 * SB + 1 * 32 + quad * 8];
            const bf16x8 afh2 = *(const bf16x8*)&hb[l16 * SB + 2 * 32 + quad * 8];
            const bf16x8 afh3 = *(const bf16x8*)&hb[l16 * SB + 3 * 32 + quad * 8];
            // cand x-part issues while afh loads are in flight
            q0 = MFMA(afx[0], bcf[0][0], q0); q2 = MFMA(afx[0], bcf[1][0], q2);
            q1 = MFMA(afx[1], bcf[0][1], q1); q3 = MFMA(afx[1], bcf[1][1], q3);
            q0 = MFMA(afx[2], bcf[0][2], q0); q2 = MFMA(afx[2], bcf[1][2], q2);
            q1 = MFMA(afx[3], bcf[0][3], q1); q3 = MFMA(afx[3], bcf[1][3], q3);
            // gate h-part
            a0 = MFMA(afh0, bgf[0][4], a0); a2 = MFMA(afh0, bgf[1][4], a2);
            a4 = MFMA(afh0, bgf[2][4], a4); a6 = MFMA(afh0, bgf[3][4], a6);
            a1 = MFMA(afh1, bgf[0][5], a1); a3 = MFMA(afh1, bgf[1][5], a3);
            a5 = MFMA(afh1, bgf[2][5], a5); a7 = MFMA(afh1, bgf[3][5], a7);
            a0 = MFMA(afh2, bgf[0][6], a0); a2 = MFMA(afh2, bgf[1][6], a2);
            a4 = MFMA(afh2, bgf[2][6], a4); a6 = MFMA(afh2, bgf[3][6], a6);
            a1 = MFMA(afh3, bgf[0][7], a1); a3 = MFMA(afh3, bgf[1][7], a3);
            a5 = MFMA(afh3, bgf[2][7], a5); a7 = MFMA(afh3, bgf[3][7], a7);
        }

        // stage x(t+1) into the other buffer; then prefetch x(t+2)
        if (t + 1 < tmax) {
            ushort4 v; v.x = f2bf(xpre.x); v.y = f2bf(xpre.y); v.z = f2bf(xpre.z); v.w = f2bf(xpre.w);
            *(ushort4*)&xb[(t + 1) & 1][srow * SB + sseg * 4] = v;
            if (t + 2 < tmax)
                xpre = *(const float4*)&X[((long)(b0 + srow) * TT + (t + 2)) * DD + sseg * 4];
        }

        // ---- gate epilogue (full-lane via xor-32 redistribution) ----
        const f32x4 gr0 = a0 + a1;   // r-gate, col c0
        const f32x4 gr1 = a2 + a3;   // r-gate, col c1
        const f32x4 gu0 = a4 + a5;   // u-gate, col c0+128
        const f32x4 gu1 = a6 + a7;   // u-gate, col c1+128
        const float r02 = __shfl_xor(gr0[2], 32, 64), r03 = __shfl_xor(gr0[3], 32, 64);
        const float r12 = __shfl_xor(gr1[2], 32, 64), r13 = __shfl_xor(gr1[3], 32, 64);
        const float u02 = __shfl_xor(gu0[2], 32, 64), u03 = __shfl_xor(gu0[3], 32, 64);
        const float u12 = __shfl_xor(gu1[2], 32, 64), u13 = __shfl_xor(gu1[3], 32, 64);
        float ug00, ug01, ug10, ug11;   // att * sigmoid(u), [row][col]
        {
            // col c0
            const float rs00 = sigm((top ? r02 : gr0[0]) + bgr0);   // row r0
            const float rs10 = sigm((top ? r03 : gr0[1]) + bgr0);   // row r0+1
            rh[r0 * SB + c0]       = f2bf(rs00 * h00);
            rh[(r0 + 1) * SB + c0] = f2bf(rs10 * h10);
            ug00 = at0 * sigm((top ? u02 : gu0[0]) + bgu0);
            ug10 = at1 * sigm((top ? u03 : gu0[1]) + bgu0);
            // col c1
            const float rs01 = sigm((top ? r12 : gr1[0]) + bgr1);
            const float rs11 = sigm((top ? r13 : gr1[1]) + bgr1);
            rh[r0 * SB + c1]       = f2bf(rs01 * h01);
            rh[(r0 + 1) * SB + c1] = f2bf(rs11 * h11);
            ug01 = at0 * sigm((top ? u12 : gu1[0]) + bgu1);
            ug11 = at1 * sigm((top ? u13 : gu1[1]) + bgu1);
        }
        lds_barrier();   // SYNC B: rh + x(t+1) visible

        // ---- cand rh-part + gate x-part(t+1) + cand epilogue ----
        const bool more = (t + 1 < tmax);
        bf16x8 afx2[4];
        {
            const bf16x8 afr0 = *(const bf16x8*)&rh[l16 * SB + 0 * 32 + quad * 8];
            const bf16x8 afr1 = *(const bf16x8*)&rh[l16 * SB + 1 * 32 + quad * 8];
            const bf16x8 afr2 = *(const bf16x8*)&rh[l16 * SB + 2 * 32 + quad * 8];
            const bf16x8 afr3 = *(const bf16x8*)&rh[l16 * SB + 3 * 32 + quad * 8];
            if (more) {
                const unsigned short* xn = &xb[(t + 1) & 1][0];
                #pragma unroll
                for (int kk = 0; kk < 4; ++kk)
                    afx2[kk] = *(const bf16x8*)&xn[l16 * SB + kk * 32 + quad * 8];
            }
            q0 = MFMA(afr0, bcf[0][4], q0);   q2 = MFMA(afr0, bcf[1][4], q2);
            q1 = MFMA(afr1, bcf[0][5], q1);   q3 = MFMA(afr1, bcf[1][5], q3);
            q0 = MFMA(afr2, bcf[0][6], q0);   q2 = MFMA(afr2, bcf[1][6], q2);
            q1 = MFMA(afr3, bcf[0][7], q1);   q3 = MFMA(afr3, bcf[1][7], q3);
        }
        // gate x-part for t+1 (independent of cand epilogue; overlaps it)
        ZERO_A;
        if (more) { GATE_X_PART(afx2); }

        const f32x4 cc0 = q0 + q1;   // col c0
        const f32x4 cc1 = q2 + q3;   // col c1
        const float c02 = __shfl_xor(cc0[2], 32, 64), c03 = __shfl_xor(cc0[3], 32, 64);
        const float c12 = __shfl_xor(cc1[2], 32, 64), c13 = __shfl_xor(cc1[3], 32, 64);

        // ---- update epilogue (full-lane, register h/u) ----
        {
            const bool v0 = t < sl0;   // row r0 valid
            const bool v1 = t < sl1;   // row r0+1 valid
            // (row r0, col c0)
            {
                const float xv = (top ? c02 : cc0[0]) + bc0v;
                const float e  = __expf(2.0f * xv);
                const float cd = 1.0f - 2.0f * __builtin_amdgcn_rcpf(e + 1.0f);
                const float nh = fmaf(ug00, cd - h00, h00);
                h00 = v0 ? nh : h00;
                hb[r0 * SB + c0] = f2bf(h00);
                OUT[((long)(b0 + r0) * TT + t) * HH + c0] = v0 ? nh : 0.f;
            }
            // (row r0+1, col c0)
            {
                const float xv = (top ? c03 : cc0[1]) + bc0v;
                const float e  = __expf(2.0f * xv);
                const float cd = 1.0f - 2.0f * __builtin_amdgcn_rcpf(e + 1.0f);
                const float nh = fmaf(ug10, cd - h10, h10);
                h10 = v1 ? nh : h10;
                hb[(r0 + 1) * SB + c0] = f2bf(h10);
                OUT[((long)(b0 + r0 + 1) * TT + t) * HH + c0] = v1 ? nh : 0.f;
            }
            // (row r0, col c1)
            {
                const float xv = (top ? c12 : cc1[0]) + bc1v;
                const float e  = __expf(2.0f * xv);
                const float cd = 1.0f - 2.0f * __builtin_amdgcn_rcpf(e + 1.0f);
                const float nh = fmaf(ug01, cd - h01, h01);
                h01 = v0 ? nh : h01;
                hb[r0 * SB + c1] = f2bf(h01);
                OUT[((long)(b0 + r0) * TT + t) * HH + c1] = v0 ? nh : 0.f;
            }
            // (row r0+1, col c1)
            {
                const float xv = (top ? c13 : cc1[1]) + bc1v;
                const float e  = __expf(2.0f * xv);
                const float cd = 1.0f - 2.0f * __builtin_amdgcn_rcpf(e + 1.0f);
                const float nh = fmaf(ug11, cd - h11, h11);
                h11 = v1 ? nh : h11;
                hb[(r0 + 1) * SB + c1] = f2bf(h11);
                OUT[((long)(b0 + r0 + 1) * TT + t) * HH + c1] = v1 ? nh : 0.f;
            }
        }
        lds_barrier();   // SYNC A for t+1: h (and staged x) ready

        if (more) {
            afx[0] = afx2[0]; afx[1] = afx2[1];
            afx[2] = afx2[2]; afx[3] = afx2[3];
        }
    }

    // tail: outputs for t in [tmax, TT) are zeros
    const int n4 = (TT - tmax) * (HH / 4);
    for (int r = 0; r < BM; ++r) {
        float4* p = (float4*)(OUT + ((long)(b0 + r) * TT + tmax) * HH);
        for (int i = tid; i < n4; i += NTH) p[i] = make_float4(0.f, 0.f, 0.f, 0.f);
    }
}

extern "C" void kernel_launch(void* const* d_in, const int* in_sizes, int n_in,
                              void* d_out, int out_size, void* d_ws, size_t ws_size,
                              hipStream_t stream) {
    (void)in_sizes; (void)n_in; (void)d_ws; (void)ws_size; (void)out_size;
    const float* X   = (const float*)d_in[0];
    const float* ATT = (const float*)d_in[1];
    const int*   SL  = (const int*)d_in[2];
    const float* WG  = (const float*)d_in[3];
    const float* BG  = (const float*)d_in[4];
    const float* WC  = (const float*)d_in[5];
    const float* BC  = (const float*)d_in[6];
    float*       OUT = (float*)d_out;
    hipLaunchKernelGGL(augru_kernel, dim3(BB / BM), dim3(NTH), 0, stream,
                       X, ATT, SL, WG, BG, WC, BC, OUT);
}